// Round 8
// baseline (9185.180 us; speedup 1.0000x reference)
//
#include <hip/hip_runtime.h>
#include <hip/hip_bf16.h>
#include <math.h>

#define NN 50000
#define EE 800000
#define TT 24
#define HID 128

// K layout for the fused GEMM operand [x(16) | xl(16) | h(128) | hl(128)] = 288
static constexpr int KTOT = 288;

typedef __attribute__((ext_vector_type(8))) short v8s;   // 8 bf16 = 4 VGPR (MFMA A/B frag)
typedef __attribute__((ext_vector_type(4))) float v4f;   // MFMA C/D frag

// fast device math: v_exp_f32-based sigmoid/tanh, saturation-safe
__device__ __forceinline__ float fast_sigmoid(float v) {
    float e = __expf(-v);
    return __builtin_amdgcn_rcpf(1.0f + e);
}
__device__ __forceinline__ float fast_tanh(float v) {
    float e2 = __expf(2.0f * v);
    return 1.0f - 2.0f * __builtin_amdgcn_rcpf(e2 + 1.0f);
}

// ---- exact 3-way bf16 split: v ~= b0 + b1 + b2 (24 mantissa bits, res ~2^-25) ----
__device__ __forceinline__ unsigned short f2bf(float v) {
    __hip_bfloat16 b = __float2bfloat16(v);   // RNE
    return *reinterpret_cast<unsigned short*>(&b);
}
__device__ __forceinline__ float bf2f(unsigned short u) {
    __hip_bfloat16 b = *reinterpret_cast<__hip_bfloat16*>(&u);
    return __bfloat162float(b);
}
__device__ __forceinline__ void split3(float v, unsigned short& u0, unsigned short& u1, unsigned short& u2) {
    u0 = f2bf(v);  float r1 = v - bf2f(u0);
    u1 = f2bf(r1); float r2 = r1 - bf2f(u1);
    u2 = f2bf(r2);
}

// ---------------- preprocessing kernels ----------------

__global__ void count_deg_kernel(const int* __restrict__ src, const int* __restrict__ dst,
                                 int* __restrict__ deg_src, int* __restrict__ cnt_dst) {
    int e = blockIdx.x * blockDim.x + threadIdx.x;
    if (e < EE) {
        atomicAdd(&deg_src[src[e]], 1);
        atomicAdd(&cnt_dst[dst[e]], 1);
    }
}

__global__ void dinv_kernel(const int* __restrict__ deg, float* __restrict__ dinv) {
    int i = blockIdx.x * blockDim.x + threadIdx.x;
    if (i < NN) {
        int d = deg[i];
        dinv[i] = (d > 0) ? 1.0f / sqrtf((float)d) : 0.0f;
    }
}

__global__ void scan_kernel(const int* __restrict__ cnt, int* __restrict__ row_ptr) {
    __shared__ int buf[2][1024];
    __shared__ int carry_s;
    int tid = threadIdx.x;
    if (tid == 0) carry_s = 0;
    __syncthreads();
    for (int base = 0; base < NN; base += 1024) {
        int i = base + tid;
        int v = (i < NN) ? cnt[i] : 0;
        int pb = 0;
        buf[0][tid] = v;
        __syncthreads();
        for (int off = 1; off < 1024; off <<= 1) {
            int t = buf[pb][tid] + ((tid >= off) ? buf[pb][tid - off] : 0);
            buf[pb ^ 1][tid] = t;
            pb ^= 1;
            __syncthreads();
        }
        int incl = buf[pb][tid];
        int carry = carry_s;
        if (i < NN) row_ptr[i] = carry + incl - v;
        __syncthreads();
        if (tid == 0) carry_s = carry + buf[pb][1023];
        __syncthreads();
    }
    if (tid == 0) row_ptr[NN] = carry_s;
}

__global__ void fill_csr_kernel(const int* __restrict__ src, const int* __restrict__ dst,
                                const int* __restrict__ row_ptr, int* __restrict__ fillp,
                                const float* __restrict__ dinv,
                                int2* __restrict__ csr) {
    int e = blockIdx.x * blockDim.x + threadIdx.x;
    if (e < EE) {
        int s = src[e], d = dst[e];
        int p = row_ptr[d] + atomicAdd(&fillp[d], 1);
        float w = -(dinv[s] * dinv[d]);
        csr[p] = make_int2(s, __float_as_int(w));
    }
}

// Build split + TRANSPOSED weights: WT[col][k] (k=0..287) as 3 bf16 planes, + summed biases.
// Stage A cols 0..255 (g = col>>7 selects z/r), stage B cols 0..127 (gate h~ = index 2).
__global__ void pack_weights_kernel(const float* __restrict__ Wx, const float* __restrict__ bx,
                                    const float* __restrict__ Wh, const float* __restrict__ bh,
                                    unsigned short* __restrict__ WA0, unsigned short* __restrict__ WA1,
                                    unsigned short* __restrict__ WA2,
                                    unsigned short* __restrict__ WB0, unsigned short* __restrict__ WB1,
                                    unsigned short* __restrict__ WB2,
                                    float* __restrict__ biasA, float* __restrict__ biasB) {
    const int NAW = 256 * KTOT, NBW = 128 * KTOT;
    int idx = blockIdx.x * blockDim.x + threadIdx.x;
    if (idx < NAW) {
        int j = idx / KTOT, k = idx % KTOT;
        int g = j >> 7, jj = j & 127;
        float v;
        if (k < 16)       v = (k < 11) ? Wx[((g*2 + 0)*11 + k) * 128 + jj] : 0.0f;
        else if (k < 32)  { int kk = k - 16; v = (kk < 11) ? Wx[((g*2 + 1)*11 + kk) * 128 + jj] : 0.0f; }
        else if (k < 160) v = Wh[((g*2 + 0)*128 + (k - 32)) * 128 + jj];
        else              v = Wh[((g*2 + 1)*128 + (k - 160)) * 128 + jj];
        unsigned short u0, u1, u2; split3(v, u0, u1, u2);
        WA0[idx] = u0; WA1[idx] = u1; WA2[idx] = u2;
    } else if (idx < NAW + NBW) {
        int t = idx - NAW;
        int j = t / KTOT, k = t % KTOT;
        int jj = j;
        float v;
        if (k < 16)       v = (k < 11) ? Wx[(4*11 + k) * 128 + jj] : 0.0f;
        else if (k < 32)  { int kk = k - 16; v = (kk < 11) ? Wx[(5*11 + kk) * 128 + jj] : 0.0f; }
        else if (k < 160) v = Wh[(4*128 + (k - 32)) * 128 + jj];
        else              v = Wh[(5*128 + (k - 160)) * 128 + jj];
        unsigned short u0, u1, u2; split3(v, u0, u1, u2);
        WB0[t] = u0; WB1[t] = u1; WB2[t] = u2;
    } else if (idx < NAW + NBW + 256) {
        int j = idx - (NAW + NBW);
        int g = j >> 7, jj = j & 127;
        biasA[j] = bx[g*128 + jj] + bh[g*128 + jj];
    } else if (idx < NAW + NBW + 256 + 128) {
        int jj = idx - (NAW + NBW + 256);
        biasB[jj] = bx[2*128 + jj] + bh[2*128 + jj];
    }
}

// ---------------- per-step kernels ----------------
// xbuf: fp32 [N][16] (cols 11-15 zero) for lap gather; X0p/X1p/X2p: bf16 planes [N][32]
// (cols 0-15 = x splits, 16-31 = xl splits written by lap_small).

__global__ void copy_x0_kernel(const float* __restrict__ Xin, float* __restrict__ xbuf,
                               unsigned short* __restrict__ X0p, unsigned short* __restrict__ X1p,
                               unsigned short* __restrict__ X2p) {
    int i = blockIdx.x * blockDim.x + threadIdx.x;
    if (i >= NN) return;
    float vals[16];
    #pragma unroll
    for (int c = 0; c < 11; c++) vals[c] = Xin[(size_t)i*11 + c];
    #pragma unroll
    for (int c = 11; c < 16; c++) vals[c] = 0.0f;
    #pragma unroll
    for (int c = 0; c < 16; c++) {
        xbuf[(size_t)i*16 + c] = vals[c];
        unsigned short u0, u1, u2; split3(vals[c], u0, u1, u2);
        X0p[(size_t)i*32 + c] = u0; X1p[(size_t)i*32 + c] = u1; X2p[(size_t)i*32 + c] = u2;
    }
}

__global__ void build_x_kernel(const float* __restrict__ Xt, const float* __restrict__ Xtm1,
                               const float* __restrict__ pos, const float* __restrict__ prevbase,
                               int prev_stride, int prev_off,
                               float* __restrict__ xbuf,
                               unsigned short* __restrict__ X0p, unsigned short* __restrict__ X1p,
                               unsigned short* __restrict__ X2p) {
    int i = blockIdx.x * blockDim.x + threadIdx.x;
    if (i >= NN) return;
    const float* xo = Xt + (size_t)i * 11;
    float tnow  = xo[6];
    float tprev = Xtm1[(size_t)i * 11 + 6];
    float inv = 1.0f / (tnow - tprev);
    float p0 = pos[(size_t)i*3 + 0], p1 = pos[(size_t)i*3 + 1], p2 = pos[(size_t)i*3 + 2];
    const float* pp = prevbase + (size_t)i * prev_stride + prev_off;
    float vals[16];
    vals[0] = xo[0]; vals[1] = xo[1]; vals[2] = xo[2];
    vals[3] = p0;    vals[4] = p1;    vals[5] = p2;
    vals[6] = tnow;  vals[7] = xo[7];
    vals[8] = (p0 - pp[0]) * inv; vals[9] = (p1 - pp[1]) * inv; vals[10] = (p2 - pp[2]) * inv;
    vals[11] = vals[12] = vals[13] = vals[14] = vals[15] = 0.0f;
    #pragma unroll
    for (int c = 0; c < 16; c++) {
        xbuf[(size_t)i*16 + c] = vals[c];
        unsigned short u0, u1, u2; split3(vals[c], u0, u1, u2);
        X0p[(size_t)i*32 + c] = u0; X1p[(size_t)i*32 + c] = u1; X2p[(size_t)i*32 + c] = u2;
    }
}

// xl = L_hat @ x (16 cols incl. zero pads); writes split planes into cols 16-31 of X*p
__global__ void lap_small_kernel(const int* __restrict__ row_ptr, const int2* __restrict__ csr,
                                 const float* __restrict__ xbuf,
                                 unsigned short* __restrict__ X0p, unsigned short* __restrict__ X1p,
                                 unsigned short* __restrict__ X2p) {
    int node = blockIdx.x * 16 + (threadIdx.x >> 4);
    int f = threadIdx.x & 15;
    if (node >= NN) return;
    int b = row_ptr[node], e = row_ptr[node + 1];
    float acc = 0.0f;
    for (int p = b; p < e; p++) {
        int2 ed = csr[p];
        acc += __int_as_float(ed.y) * xbuf[(size_t)ed.x*16 + f];
    }
    unsigned short u0, u1, u2; split3(acc, u0, u1, u2);
    X0p[(size_t)node*32 + 16 + f] = u0;
    X1p[(size_t)node*32 + 16 + f] = u1;
    X2p[(size_t)node*32 + 16 + f] = u2;
}

// lap over fp32 [N][128] input; output = split planes written into cols 128-255 of H*p [N][256]
__global__ __launch_bounds__(256)
void lap_big_kernel(const int* __restrict__ row_ptr, const int2* __restrict__ csr,
                    const float* __restrict__ hin,
                    unsigned short* __restrict__ H0p, unsigned short* __restrict__ H1p,
                    unsigned short* __restrict__ H2p) {
    int tid  = threadIdx.x;
    int node = blockIdx.x * 4 + (tid >> 6);
    if (node >= NN) return;
    int eo = (tid >> 5) & 1;
    int f  = tid & 31;
    const float4* h4 = (const float4*)hin;
    float4 acc0 = make_float4(0.f, 0.f, 0.f, 0.f);
    float4 acc1 = make_float4(0.f, 0.f, 0.f, 0.f);
    int b = row_ptr[node], e = row_ptr[node + 1];
    int p = b;
    for (; p + 3 < e; p += 4) {
        int2 ea = csr[p + eo];
        int2 eb = csr[p + 2 + eo];
        float wa = __int_as_float(ea.y);
        float wb = __int_as_float(eb.y);
        float4 va = h4[(size_t)ea.x*32 + f];
        float4 vb = h4[(size_t)eb.x*32 + f];
        acc0.x += wa * va.x; acc0.y += wa * va.y; acc0.z += wa * va.z; acc0.w += wa * va.w;
        acc1.x += wb * vb.x; acc1.y += wb * vb.y; acc1.z += wb * vb.z; acc1.w += wb * vb.w;
    }
    for (; p + 1 < e; p += 2) {
        int2 ea = csr[p + eo];
        float wa = __int_as_float(ea.y);
        float4 va = h4[(size_t)ea.x*32 + f];
        acc0.x += wa * va.x; acc0.y += wa * va.y; acc0.z += wa * va.z; acc0.w += wa * va.w;
    }
    if (p < e && eo == 0) {
        int2 ea = csr[p];
        float wa = __int_as_float(ea.y);
        float4 va = h4[(size_t)ea.x*32 + f];
        acc0.x += wa * va.x; acc0.y += wa * va.y; acc0.z += wa * va.z; acc0.w += wa * va.w;
    }
    acc0.x += acc1.x; acc0.y += acc1.y; acc0.z += acc1.z; acc0.w += acc1.w;
    acc0.x += __shfl_xor(acc0.x, 32);
    acc0.y += __shfl_xor(acc0.y, 32);
    acc0.z += __shfl_xor(acc0.z, 32);
    acc0.w += __shfl_xor(acc0.w, 32);
    if (eo == 0) {
        size_t base = (size_t)node*256 + 128 + f*4;
        float a[4] = {acc0.x, acc0.y, acc0.z, acc0.w};
        ushort4 s0, s1, s2;
        unsigned short u0, u1, u2;
        split3(a[0], u0, u1, u2); s0.x = u0; s1.x = u1; s2.x = u2;
        split3(a[1], u0, u1, u2); s0.y = u0; s1.y = u1; s2.y = u2;
        split3(a[2], u0, u1, u2); s0.z = u0; s1.z = u1; s2.z = u2;
        split3(a[3], u0, u1, u2); s0.w = u0; s1.w = u1; s2.w = u2;
        *(ushort4*)(H0p + base) = s0;
        *(ushort4*)(H1p + base) = s1;
        *(ushort4*)(H2p + base) = s2;
    }
}

// ---------------- MFMA GEMM (exact via 3-way bf16 split, 6 cross-product passes) ----------------
// C = [x|xl|h|hl] @ W + bias. No LDS, no barriers: A-frags ([row][k] 16B/lane) and
// pre-transposed W-frags ([col][k] 16B/lane) load straight from L1/L2.
// Block = 64x64 (4 waves, each one 32x32 = 2x2 mfma_f32_16x16x32_bf16 tiles).
// Frag layouts (CDNA): A/B: idx=lane&15 (row/col), k=(lane>>4)*8+e. D: col=lane&15, row=(lane>>4)*4+r.
template<int NOUT, int EPI>
__global__ __launch_bounds__(256)
void gemm_mfma_kernel(const unsigned short* __restrict__ X0p, const unsigned short* __restrict__ X1p,
                      const unsigned short* __restrict__ X2p,
                      const unsigned short* __restrict__ H0p, const unsigned short* __restrict__ H1p,
                      const unsigned short* __restrict__ H2p,
                      const unsigned short* __restrict__ W0, const unsigned short* __restrict__ W1,
                      const unsigned short* __restrict__ W2,
                      const float* __restrict__ bias,
                      float* __restrict__ p0, float* __restrict__ p1, const float* __restrict__ p2,
                      unsigned short* __restrict__ S0, unsigned short* __restrict__ S1,
                      unsigned short* __restrict__ S2)
{
    const int tid  = threadIdx.x;
    const int lane = tid & 63, wid = tid >> 6;
    const int l15 = lane & 15, chunk = lane >> 4;
    const int row0 = blockIdx.x * 64 + (wid >> 1) * 32;
    const int col0 = blockIdx.y * 64 + (wid & 1) * 32;
    int ar0 = row0 + l15;      if (ar0 >= NN) ar0 = NN - 1;
    int ar1 = row0 + 16 + l15; if (ar1 >= NN) ar1 = NN - 1;
    const int bc0 = col0 + l15, bc1 = col0 + 16 + l15;

    v4f acc[2][2];
    v4f z4 = {0.f, 0.f, 0.f, 0.f};
    acc[0][0] = z4; acc[0][1] = z4; acc[1][0] = z4; acc[1][1] = z4;

    v8s a0[2], a1[2], a2[2], b0[2], b1[2], b2[2];

    // k-step 0: [x|xl] segment from X planes [N][32]
    {
        size_t oa0 = (size_t)ar0*32 + chunk*8, oa1 = (size_t)ar1*32 + chunk*8;
        size_t ob0 = (size_t)bc0*KTOT + chunk*8, ob1 = (size_t)bc1*KTOT + chunk*8;
        a0[0] = *(const v8s*)(X0p + oa0); a1[0] = *(const v8s*)(X1p + oa0); a2[0] = *(const v8s*)(X2p + oa0);
        a0[1] = *(const v8s*)(X0p + oa1); a1[1] = *(const v8s*)(X1p + oa1); a2[1] = *(const v8s*)(X2p + oa1);
        b0[0] = *(const v8s*)(W0 + ob0);  b1[0] = *(const v8s*)(W1 + ob0);  b2[0] = *(const v8s*)(W2 + ob0);
        b0[1] = *(const v8s*)(W0 + ob1);  b1[1] = *(const v8s*)(W1 + ob1);  b2[1] = *(const v8s*)(W2 + ob1);
        #pragma unroll
        for (int mi = 0; mi < 2; mi++)
            #pragma unroll
            for (int ni = 0; ni < 2; ni++) {
                v4f c = acc[mi][ni];
                c = __builtin_amdgcn_mfma_f32_16x16x32_bf16(a0[mi], b0[ni], c, 0, 0, 0);
                c = __builtin_amdgcn_mfma_f32_16x16x32_bf16(a0[mi], b1[ni], c, 0, 0, 0);
                c = __builtin_amdgcn_mfma_f32_16x16x32_bf16(a1[mi], b0[ni], c, 0, 0, 0);
                c = __builtin_amdgcn_mfma_f32_16x16x32_bf16(a0[mi], b2[ni], c, 0, 0, 0);
                c = __builtin_amdgcn_mfma_f32_16x16x32_bf16(a1[mi], b1[ni], c, 0, 0, 0);
                c = __builtin_amdgcn_mfma_f32_16x16x32_bf16(a2[mi], b0[ni], c, 0, 0, 0);
                acc[mi][ni] = c;
            }
    }
    // k-steps 1..8: h/hl segment from H planes [N][256]
    #pragma unroll
    for (int ks = 1; ks < 9; ks++) {
        int ka = (ks - 1) * 32 + chunk * 8;
        int kb = ks * 32 + chunk * 8;
        size_t oa0 = (size_t)ar0*256 + ka, oa1 = (size_t)ar1*256 + ka;
        size_t ob0 = (size_t)bc0*KTOT + kb, ob1 = (size_t)bc1*KTOT + kb;
        a0[0] = *(const v8s*)(H0p + oa0); a1[0] = *(const v8s*)(H1p + oa0); a2[0] = *(const v8s*)(H2p + oa0);
        a0[1] = *(const v8s*)(H0p + oa1); a1[1] = *(const v8s*)(H1p + oa1); a2[1] = *(const v8s*)(H2p + oa1);
        b0[0] = *(const v8s*)(W0 + ob0);  b1[0] = *(const v8s*)(W1 + ob0);  b2[0] = *(const v8s*)(W2 + ob0);
        b0[1] = *(const v8s*)(W0 + ob1);  b1[1] = *(const v8s*)(W1 + ob1);  b2[1] = *(const v8s*)(W2 + ob1);
        #pragma unroll
        for (int mi = 0; mi < 2; mi++)
            #pragma unroll
            for (int ni = 0; ni < 2; ni++) {
                v4f c = acc[mi][ni];
                c = __builtin_amdgcn_mfma_f32_16x16x32_bf16(a0[mi], b0[ni], c, 0, 0, 0);
                c = __builtin_amdgcn_mfma_f32_16x16x32_bf16(a0[mi], b1[ni], c, 0, 0, 0);
                c = __builtin_amdgcn_mfma_f32_16x16x32_bf16(a1[mi], b0[ni], c, 0, 0, 0);
                c = __builtin_amdgcn_mfma_f32_16x16x32_bf16(a0[mi], b2[ni], c, 0, 0, 0);
                c = __builtin_amdgcn_mfma_f32_16x16x32_bf16(a1[mi], b1[ni], c, 0, 0, 0);
                c = __builtin_amdgcn_mfma_f32_16x16x32_bf16(a2[mi], b0[ni], c, 0, 0, 0);
                acc[mi][ni] = c;
            }
    }

    // epilogue: D layout col=lane&15, row=(lane>>4)*4+r
    #pragma unroll
    for (int mi = 0; mi < 2; mi++)
        #pragma unroll
        for (int ni = 0; ni < 2; ni++) {
            int cc = col0 + ni*16 + l15;
            float bv = bias[cc];
            #pragma unroll
            for (int r = 0; r < 4; r++) {
                int row = row0 + mi*16 + chunk*4 + r;
                if (row >= NN) continue;
                float v = acc[mi][ni][r] + bv;
                if (EPI == 0) {
                    float s = fast_sigmoid(v);
                    if (cc < HID) {
                        p0[(size_t)row*HID + cc] = s;                      // z
                    } else {
                        int c = cc - HID;
                        float hr = p2[(size_t)row*HID + c] * s;            // hr = h*r
                        p1[(size_t)row*HID + c] = hr;
                        unsigned short u0, u1, u2; split3(hr, u0, u1, u2);
                        S0[(size_t)row*256 + c] = u0;
                        S1[(size_t)row*256 + c] = u1;
                        S2[(size_t)row*256 + c] = u2;
                    }
                } else {
                    float ht = fast_tanh(v);
                    float zz   = p0[(size_t)row*HID + cc];
                    float hold = p1[(size_t)row*HID + cc];
                    float hn = zz*hold + (1.0f - zz)*ht;                   // h update
                    p1[(size_t)row*HID + cc] = hn;
                    unsigned short u0, u1, u2; split3(hn, u0, u1, u2);
                    S0[(size_t)row*256 + cc] = u0;
                    S1[(size_t)row*256 + cc] = u1;
                    S2[(size_t)row*256 + cc] = u2;
                }
            }
        }
}

// u = h @ W_head + b_head ; 64 lanes per node (2 h-elems each), shfl reduce
__global__ void head_kernel(const float* __restrict__ h, const float* __restrict__ Whead,
                            const float* __restrict__ bhead, float* __restrict__ out) {
    int node = blockIdx.x * 4 + (threadIdx.x >> 6);
    int lane = threadIdx.x & 63;
    if (node >= NN) return;
    float h0 = h[(size_t)node*128 + lane];
    float h1 = h[(size_t)node*128 + 64 + lane];
    float p[3];
    #pragma unroll
    for (int j = 0; j < 3; j++)
        p[j] = h0 * Whead[lane*3 + j] + h1 * Whead[(64 + lane)*3 + j];
    #pragma unroll
    for (int off = 32; off > 0; off >>= 1) {
        p[0] += __shfl_down(p[0], off);
        p[1] += __shfl_down(p[1], off);
        p[2] += __shfl_down(p[2], off);
    }
    if (lane == 0) {
        out[(size_t)node*3 + 0] = p[0] + bhead[0];
        out[(size_t)node*3 + 1] = p[1] + bhead[1];
        out[(size_t)node*3 + 2] = p[2] + bhead[2];
    }
}

// ---------------- host launch ----------------

extern "C" void kernel_launch(void* const* d_in, const int* in_sizes, int n_in,
                              void* d_out, int out_size, void* d_ws, size_t ws_size,
                              hipStream_t stream) {
    const float* X_seq  = (const float*)d_in[0];   // [24,50000,11]
    const int*   eidx   = (const int*)  d_in[1];   // [2,800000]
    const float* Wx     = (const float*)d_in[2];   // [3,2,11,128]
    const float* bx     = (const float*)d_in[3];   // [3,128]
    const float* Wh     = (const float*)d_in[4];   // [3,2,128,128]
    const float* bh     = (const float*)d_in[5];   // [3,128]
    const float* Whead  = (const float*)d_in[6];   // [128,3]
    const float* bhead  = (const float*)d_in[7];   // [3]
    float* out = (float*)d_out;                    // [24,50000,3]

    const int* src = eidx;
    const int* dst = eidx + EE;

    char* base = (char*)d_ws;
    size_t off = 0;
    auto carve = [&](size_t bytes) -> void* {
        void* p = base + off;
        off += (bytes + 255) & ~(size_t)255;
        return p;
    };
    int*   deg_i   = (int*)  carve((size_t)NN * 4);
    int*   cnt     = (int*)  carve((size_t)NN * 4);
    int*   fillp   = (int*)  carve((size_t)NN * 4);
    int*   row_ptr = (int*)  carve((size_t)(NN + 1) * 4);
    float* dinv    = (float*)carve((size_t)NN * 4);
    int2*  csr     = (int2*) carve((size_t)EE * 8);
    unsigned short* WA0 = (unsigned short*)carve((size_t)256 * KTOT * 2);
    unsigned short* WA1 = (unsigned short*)carve((size_t)256 * KTOT * 2);
    unsigned short* WA2 = (unsigned short*)carve((size_t)256 * KTOT * 2);
    unsigned short* WB0 = (unsigned short*)carve((size_t)128 * KTOT * 2);
    unsigned short* WB1 = (unsigned short*)carve((size_t)128 * KTOT * 2);
    unsigned short* WB2 = (unsigned short*)carve((size_t)128 * KTOT * 2);
    float* biasA   = (float*)carve(256 * 4);
    float* biasB   = (float*)carve(128 * 4);
    float* xbuf    = (float*)carve((size_t)NN * 16 * 4);
    unsigned short* X0p = (unsigned short*)carve((size_t)NN * 32 * 2);
    unsigned short* X1p = (unsigned short*)carve((size_t)NN * 32 * 2);
    unsigned short* X2p = (unsigned short*)carve((size_t)NN * 32 * 2);
    float* hbuf    = (float*)carve((size_t)NN * 128 * 4);
    unsigned short* HA0 = (unsigned short*)carve((size_t)NN * 256 * 2);  // [h | hl] splits
    unsigned short* HA1 = (unsigned short*)carve((size_t)NN * 256 * 2);
    unsigned short* HA2 = (unsigned short*)carve((size_t)NN * 256 * 2);
    float* hrbuf   = (float*)carve((size_t)NN * 128 * 4);
    unsigned short* HB0 = (unsigned short*)carve((size_t)NN * 256 * 2);  // [hr | hrl] splits
    unsigned short* HB1 = (unsigned short*)carve((size_t)NN * 256 * 2);
    unsigned short* HB2 = (unsigned short*)carve((size_t)NN * 256 * 2);
    float* zbuf    = (float*)carve((size_t)NN * 128 * 4);
    (void)ws_size; (void)n_in; (void)in_sizes; (void)out_size;

    hipMemsetAsync(deg_i, 0, (size_t)NN * 4, stream);
    hipMemsetAsync(cnt,   0, (size_t)NN * 4, stream);
    hipMemsetAsync(fillp, 0, (size_t)NN * 4, stream);
    hipMemsetAsync(hbuf,  0, (size_t)NN * 128 * 4, stream);
    hipMemsetAsync(HA0,   0, (size_t)NN * 256 * 2, stream);   // h=0 -> zero splits at t=0
    hipMemsetAsync(HA1,   0, (size_t)NN * 256 * 2, stream);
    hipMemsetAsync(HA2,   0, (size_t)NN * 256 * 2, stream);

    count_deg_kernel<<<(EE + 255) / 256, 256, 0, stream>>>(src, dst, deg_i, cnt);
    dinv_kernel<<<(NN + 255) / 256, 256, 0, stream>>>(deg_i, dinv);
    scan_kernel<<<1, 1024, 0, stream>>>(cnt, row_ptr);
    fill_csr_kernel<<<(EE + 255) / 256, 256, 0, stream>>>(src, dst, row_ptr, fillp, dinv, csr);
    {
        int total = 256*KTOT + 128*KTOT + 256 + 128;
        pack_weights_kernel<<<(total + 255) / 256, 256, 0, stream>>>(Wx, bx, Wh, bh,
            WA0, WA1, WA2, WB0, WB1, WB2, biasA, biasB);
    }

    const int gridN256 = (NN + 255) / 256;
    const int gridM = (NN + 63) / 64;                 // 782
    const dim3 gridGA(gridM, 4);                      // 64-col blocks over 256 cols
    const dim3 gridGB(gridM, 2);                      // over 128 cols

    for (int t = 0; t < TT; t++) {
        if (t == 0) {
            copy_x0_kernel<<<gridN256, 256, 0, stream>>>(X_seq, xbuf, X0p, X1p, X2p);
        } else {
            const float* Xt   = X_seq + (size_t)t * NN * 11;
            const float* Xtm1 = X_seq + (size_t)(t - 1) * NN * 11;
            const float* pos  = out + (size_t)(t - 1) * NN * 3;
            const float* prevbase;
            int pstride, poff;
            if (t == 1) { prevbase = X_seq; pstride = 11; poff = 3; }
            else        { prevbase = out + (size_t)(t - 2) * NN * 3; pstride = 3; poff = 0; }
            build_x_kernel<<<gridN256, 256, 0, stream>>>(Xt, Xtm1, pos, prevbase, pstride, poff,
                                                         xbuf, X0p, X1p, X2p);
        }

        lap_small_kernel<<<(NN + 15) / 16, 256, 0, stream>>>(row_ptr, csr, xbuf, X0p, X1p, X2p);
        lap_big_kernel<<<(NN + 3) / 4, 256, 0, stream>>>(row_ptr, csr, hbuf, HA0, HA1, HA2);

        // stage A: z (cols<128) and hr (cols>=128, also emits hr splits into HB*)
        gemm_mfma_kernel<256, 0><<<gridGA, 256, 0, stream>>>(X0p, X1p, X2p, HA0, HA1, HA2,
                                                             WA0, WA1, WA2, biasA,
                                                             zbuf, hrbuf, hbuf, HB0, HB1, HB2);
        // lap of hr -> hrl splits into HB* cols 128-255
        lap_big_kernel<<<(NN + 3) / 4, 256, 0, stream>>>(row_ptr, csr, hrbuf, HB0, HB1, HB2);

        // stage B: h~ and h update (in place on hbuf; emits h splits into HA* for step t+1)
        gemm_mfma_kernel<128, 1><<<gridGB, 256, 0, stream>>>(X0p, X1p, X2p, HB0, HB1, HB2,
                                                             WB0, WB1, WB2, biasB,
                                                             zbuf, hbuf, nullptr, HA0, HA1, HA2);

        head_kernel<<<(NN + 3) / 4, 256, 0, stream>>>(hbuf, Whead, bhead, out + (size_t)t * NN * 3);
    }
}

// Round 11
// 8780.986 us; speedup vs baseline: 1.0460x; 1.0460x over previous
//
#include <hip/hip_runtime.h>
#include <hip/hip_bf16.h>
#include <math.h>

#define NN 50000
#define EE 800000
#define TT 24
#define HID 128

// K layout for the fused GEMM operand [x(16) | xl(16) | h(128) | hl(128)] = 288
static constexpr int KTOT = 288;

typedef __attribute__((ext_vector_type(8))) short v8s;   // 8 bf16 = 4 VGPR (MFMA A/B frag)
typedef __attribute__((ext_vector_type(4))) float v4f;   // MFMA C/D frag

// fast device math: v_exp_f32-based sigmoid/tanh, saturation-safe
__device__ __forceinline__ float fast_sigmoid(float v) {
    float e = __expf(-v);
    return __builtin_amdgcn_rcpf(1.0f + e);
}
__device__ __forceinline__ float fast_tanh(float v) {
    float e2 = __expf(2.0f * v);
    return 1.0f - 2.0f * __builtin_amdgcn_rcpf(e2 + 1.0f);
}

// ---- exact 3-way bf16 split: v ~= b0 + b1 + b2 (24 mantissa bits, res ~2^-25) ----
__device__ __forceinline__ unsigned short f2bf(float v) {
    __hip_bfloat16 b = __float2bfloat16(v);   // RNE
    return *reinterpret_cast<unsigned short*>(&b);
}
__device__ __forceinline__ float bf2f(unsigned short u) {
    __hip_bfloat16 b = *reinterpret_cast<__hip_bfloat16*>(&u);
    return __bfloat162float(b);
}
__device__ __forceinline__ void split3(float v, unsigned short& u0, unsigned short& u1, unsigned short& u2) {
    u0 = f2bf(v);  float r1 = v - bf2f(u0);
    u1 = f2bf(r1); float r2 = r1 - bf2f(u1);
    u2 = f2bf(r2);
}

// ---------------- preprocessing kernels ----------------

__global__ void count_deg_kernel(const int* __restrict__ src, const int* __restrict__ dst,
                                 int* __restrict__ deg_src, int* __restrict__ cnt_dst) {
    int e = blockIdx.x * blockDim.x + threadIdx.x;
    if (e < EE) {
        atomicAdd(&deg_src[src[e]], 1);
        atomicAdd(&cnt_dst[dst[e]], 1);
    }
}

__global__ void dinv_kernel(const int* __restrict__ deg, float* __restrict__ dinv) {
    int i = blockIdx.x * blockDim.x + threadIdx.x;
    if (i < NN) {
        int d = deg[i];
        dinv[i] = (d > 0) ? 1.0f / sqrtf((float)d) : 0.0f;
    }
}

__global__ void scan_kernel(const int* __restrict__ cnt, int* __restrict__ row_ptr) {
    __shared__ int buf[2][1024];
    __shared__ int carry_s;
    int tid = threadIdx.x;
    if (tid == 0) carry_s = 0;
    __syncthreads();
    for (int base = 0; base < NN; base += 1024) {
        int i = base + tid;
        int v = (i < NN) ? cnt[i] : 0;
        int pb = 0;
        buf[0][tid] = v;
        __syncthreads();
        for (int off = 1; off < 1024; off <<= 1) {
            int t = buf[pb][tid] + ((tid >= off) ? buf[pb][tid - off] : 0);
            buf[pb ^ 1][tid] = t;
            pb ^= 1;
            __syncthreads();
        }
        int incl = buf[pb][tid];
        int carry = carry_s;
        if (i < NN) row_ptr[i] = carry + incl - v;
        __syncthreads();
        if (tid == 0) carry_s = carry + buf[pb][1023];
        __syncthreads();
    }
    if (tid == 0) row_ptr[NN] = carry_s;
}

__global__ void fill_csr_kernel(const int* __restrict__ src, const int* __restrict__ dst,
                                const int* __restrict__ row_ptr, int* __restrict__ fillp,
                                const float* __restrict__ dinv,
                                int2* __restrict__ csr) {
    int e = blockIdx.x * blockDim.x + threadIdx.x;
    if (e < EE) {
        int s = src[e], d = dst[e];
        int p = row_ptr[d] + atomicAdd(&fillp[d], 1);
        float w = -(dinv[s] * dinv[d]);
        csr[p] = make_int2(s, __float_as_int(w));
    }
}

// Build split + TRANSPOSED weights: WT[col][k] (k=0..287) as 3 bf16 planes, + summed biases.
__global__ void pack_weights_kernel(const float* __restrict__ Wx, const float* __restrict__ bx,
                                    const float* __restrict__ Wh, const float* __restrict__ bh,
                                    unsigned short* __restrict__ WA0, unsigned short* __restrict__ WA1,
                                    unsigned short* __restrict__ WA2,
                                    unsigned short* __restrict__ WB0, unsigned short* __restrict__ WB1,
                                    unsigned short* __restrict__ WB2,
                                    float* __restrict__ biasA, float* __restrict__ biasB) {
    const int NAW = 256 * KTOT, NBW = 128 * KTOT;
    int idx = blockIdx.x * blockDim.x + threadIdx.x;
    if (idx < NAW) {
        int j = idx / KTOT, k = idx % KTOT;
        int g = j >> 7, jj = j & 127;
        float v;
        if (k < 16)       v = (k < 11) ? Wx[((g*2 + 0)*11 + k) * 128 + jj] : 0.0f;
        else if (k < 32)  { int kk = k - 16; v = (kk < 11) ? Wx[((g*2 + 1)*11 + kk) * 128 + jj] : 0.0f; }
        else if (k < 160) v = Wh[((g*2 + 0)*128 + (k - 32)) * 128 + jj];
        else              v = Wh[((g*2 + 1)*128 + (k - 160)) * 128 + jj];
        unsigned short u0, u1, u2; split3(v, u0, u1, u2);
        WA0[idx] = u0; WA1[idx] = u1; WA2[idx] = u2;
    } else if (idx < NAW + NBW) {
        int t = idx - NAW;
        int j = t / KTOT, k = t % KTOT;
        int jj = j;
        float v;
        if (k < 16)       v = (k < 11) ? Wx[(4*11 + k) * 128 + jj] : 0.0f;
        else if (k < 32)  { int kk = k - 16; v = (kk < 11) ? Wx[(5*11 + kk) * 128 + jj] : 0.0f; }
        else if (k < 160) v = Wh[(4*128 + (k - 32)) * 128 + jj];
        else              v = Wh[(5*128 + (k - 160)) * 128 + jj];
        unsigned short u0, u1, u2; split3(v, u0, u1, u2);
        WB0[t] = u0; WB1[t] = u1; WB2[t] = u2;
    } else if (idx < NAW + NBW + 256) {
        int j = idx - (NAW + NBW);
        int g = j >> 7, jj = j & 127;
        biasA[j] = bx[g*128 + jj] + bh[g*128 + jj];
    } else if (idx < NAW + NBW + 256 + 128) {
        int jj = idx - (NAW + NBW + 256);
        biasB[jj] = bx[2*128 + jj] + bh[2*128 + jj];
    }
}

// ---------------- per-step kernels ----------------

__global__ void copy_x0_kernel(const float* __restrict__ Xin, float* __restrict__ xbuf,
                               unsigned short* __restrict__ X0p, unsigned short* __restrict__ X1p,
                               unsigned short* __restrict__ X2p) {
    int i = blockIdx.x * blockDim.x + threadIdx.x;
    if (i >= NN) return;
    float vals[16];
    #pragma unroll
    for (int c = 0; c < 11; c++) vals[c] = Xin[(size_t)i*11 + c];
    #pragma unroll
    for (int c = 11; c < 16; c++) vals[c] = 0.0f;
    #pragma unroll
    for (int c = 0; c < 16; c++) {
        xbuf[(size_t)i*16 + c] = vals[c];
        unsigned short u0, u1, u2; split3(vals[c], u0, u1, u2);
        X0p[(size_t)i*32 + c] = u0; X1p[(size_t)i*32 + c] = u1; X2p[(size_t)i*32 + c] = u2;
    }
}

__global__ void build_x_kernel(const float* __restrict__ Xt, const float* __restrict__ Xtm1,
                               const float* __restrict__ pos, const float* __restrict__ prevbase,
                               int prev_stride, int prev_off,
                               float* __restrict__ xbuf,
                               unsigned short* __restrict__ X0p, unsigned short* __restrict__ X1p,
                               unsigned short* __restrict__ X2p) {
    int i = blockIdx.x * blockDim.x + threadIdx.x;
    if (i >= NN) return;
    const float* xo = Xt + (size_t)i * 11;
    float tnow  = xo[6];
    float tprev = Xtm1[(size_t)i * 11 + 6];
    float inv = 1.0f / (tnow - tprev);
    float p0 = pos[(size_t)i*3 + 0], p1 = pos[(size_t)i*3 + 1], p2 = pos[(size_t)i*3 + 2];
    const float* pp = prevbase + (size_t)i * prev_stride + prev_off;
    float vals[16];
    vals[0] = xo[0]; vals[1] = xo[1]; vals[2] = xo[2];
    vals[3] = p0;    vals[4] = p1;    vals[5] = p2;
    vals[6] = tnow;  vals[7] = xo[7];
    vals[8] = (p0 - pp[0]) * inv; vals[9] = (p1 - pp[1]) * inv; vals[10] = (p2 - pp[2]) * inv;
    vals[11] = vals[12] = vals[13] = vals[14] = vals[15] = 0.0f;
    #pragma unroll
    for (int c = 0; c < 16; c++) {
        xbuf[(size_t)i*16 + c] = vals[c];
        unsigned short u0, u1, u2; split3(vals[c], u0, u1, u2);
        X0p[(size_t)i*32 + c] = u0; X1p[(size_t)i*32 + c] = u1; X2p[(size_t)i*32 + c] = u2;
    }
}

// xl = L_hat @ x (16 cols incl. zero pads); writes split planes into cols 16-31 of X*p
__global__ void lap_small_kernel(const int* __restrict__ row_ptr, const int2* __restrict__ csr,
                                 const float* __restrict__ xbuf,
                                 unsigned short* __restrict__ X0p, unsigned short* __restrict__ X1p,
                                 unsigned short* __restrict__ X2p) {
    int node = blockIdx.x * 16 + (threadIdx.x >> 4);
    int f = threadIdx.x & 15;
    if (node >= NN) return;
    int b = row_ptr[node], e = row_ptr[node + 1];
    float acc = 0.0f;
    for (int p = b; p < e; p++) {
        int2 ed = csr[p];
        acc += __int_as_float(ed.y) * xbuf[(size_t)ed.x*16 + f];
    }
    unsigned short u0, u1, u2; split3(acc, u0, u1, u2);
    X0p[(size_t)node*32 + 16 + f] = u0;
    X1p[(size_t)node*32 + 16 + f] = u1;
    X2p[(size_t)node*32 + 16 + f] = u2;
}

// lap over fp32 [N][128] input; output = split planes into cols 128-255 of H*p [N][256]
__global__ __launch_bounds__(256)
void lap_big_kernel(const int* __restrict__ row_ptr, const int2* __restrict__ csr,
                    const float* __restrict__ hin,
                    unsigned short* __restrict__ H0p, unsigned short* __restrict__ H1p,
                    unsigned short* __restrict__ H2p) {
    int tid  = threadIdx.x;
    int node = blockIdx.x * 4 + (tid >> 6);
    if (node >= NN) return;
    int eo = (tid >> 5) & 1;
    int f  = tid & 31;
    const float4* h4 = (const float4*)hin;
    float4 acc0 = make_float4(0.f, 0.f, 0.f, 0.f);
    float4 acc1 = make_float4(0.f, 0.f, 0.f, 0.f);
    int b = row_ptr[node], e = row_ptr[node + 1];
    int p = b;
    for (; p + 3 < e; p += 4) {
        int2 ea = csr[p + eo];
        int2 eb = csr[p + 2 + eo];
        float wa = __int_as_float(ea.y);
        float wb = __int_as_float(eb.y);
        float4 va = h4[(size_t)ea.x*32 + f];
        float4 vb = h4[(size_t)eb.x*32 + f];
        acc0.x += wa * va.x; acc0.y += wa * va.y; acc0.z += wa * va.z; acc0.w += wa * va.w;
        acc1.x += wb * vb.x; acc1.y += wb * vb.y; acc1.z += wb * vb.z; acc1.w += wb * vb.w;
    }
    for (; p + 1 < e; p += 2) {
        int2 ea = csr[p + eo];
        float wa = __int_as_float(ea.y);
        float4 va = h4[(size_t)ea.x*32 + f];
        acc0.x += wa * va.x; acc0.y += wa * va.y; acc0.z += wa * va.z; acc0.w += wa * va.w;
    }
    if (p < e && eo == 0) {
        int2 ea = csr[p];
        float wa = __int_as_float(ea.y);
        float4 va = h4[(size_t)ea.x*32 + f];
        acc0.x += wa * va.x; acc0.y += wa * va.y; acc0.z += wa * va.z; acc0.w += wa * va.w;
    }
    acc0.x += acc1.x; acc0.y += acc1.y; acc0.z += acc1.z; acc0.w += acc1.w;
    acc0.x += __shfl_xor(acc0.x, 32);
    acc0.y += __shfl_xor(acc0.y, 32);
    acc0.z += __shfl_xor(acc0.z, 32);
    acc0.w += __shfl_xor(acc0.w, 32);
    if (eo == 0) {
        size_t base = (size_t)node*256 + 128 + f*4;
        float a[4] = {acc0.x, acc0.y, acc0.z, acc0.w};
        ushort4 s0, s1, s2;
        unsigned short u0, u1, u2;
        split3(a[0], u0, u1, u2); s0.x = u0; s1.x = u1; s2.x = u2;
        split3(a[1], u0, u1, u2); s0.y = u0; s1.y = u1; s2.y = u2;
        split3(a[2], u0, u1, u2); s0.z = u0; s1.z = u1; s2.z = u2;
        split3(a[3], u0, u1, u2); s0.w = u0; s1.w = u1; s2.w = u2;
        *(ushort4*)(H0p + base) = s0;
        *(ushort4*)(H1p + base) = s1;
        *(ushort4*)(H2p + base) = s2;
    }
}

// ---------------- MFMA GEMM (exact 3-way bf16 split, 6 cross products) ----------------
// Reuse flipped vs round 8: each block owns 64 ROWS x ALL NOUT cols, so A-planes are
// read ONCE total (round 8's grid re-read them 4x -> 187MB HBM). W ([col][288] splits,
// 0.44MB) is re-read per block but L2-resident. No LDS, no barriers.
// Wave w handles cols [w*64, w*64+64): 4 m-frags x 4 n-frags of 16x16x32.
// Frag layouts: A/B idx=lane&15, k=(lane>>4)*8+e. D: col=lane&15, row=(lane>>4)*4+r.
template<int NOUT, int EPI>
__global__ __launch_bounds__(256)
void gemm_mfma_kernel(const unsigned short* __restrict__ X0p, const unsigned short* __restrict__ X1p,
                      const unsigned short* __restrict__ X2p,
                      const unsigned short* __restrict__ H0p, const unsigned short* __restrict__ H1p,
                      const unsigned short* __restrict__ H2p,
                      const unsigned short* __restrict__ W0, const unsigned short* __restrict__ W1,
                      const unsigned short* __restrict__ W2,
                      const float* __restrict__ bias,
                      float* __restrict__ p0, float* __restrict__ p1, const float* __restrict__ p2,
                      unsigned short* __restrict__ S0, unsigned short* __restrict__ S1,
                      unsigned short* __restrict__ S2)
{
    const int tid  = threadIdx.x;
    const int lane = tid & 63, wid = tid >> 6;
    const int l15 = lane & 15, chunk = lane >> 4;
    const int row0 = blockIdx.x * 64;
    const int wcol0 = wid * 64;                       // wave's 64-col strip within NOUT

    int ar[4];
    #pragma unroll
    for (int mi = 0; mi < 4; mi++) {
        int r = row0 + mi*16 + l15;
        ar[mi] = (r < NN) ? r : NN - 1;
    }

    v4f acc[4][4];
    v4f z4 = {0.f, 0.f, 0.f, 0.f};
    #pragma unroll
    for (int mi = 0; mi < 4; mi++)
        #pragma unroll
        for (int ni = 0; ni < 4; ni++) acc[mi][ni] = z4;

    #pragma unroll
    for (int ks = 0; ks < 9; ks++) {
        // A-frags for this k-step (wave-redundant across 4 waves -> L1 hits)
        v8s a0[4], a1[4], a2[4];
        #pragma unroll
        for (int mi = 0; mi < 4; mi++) {
            size_t oa = (ks == 0) ? ((size_t)ar[mi]*32 + chunk*8)
                                  : ((size_t)ar[mi]*256 + (ks-1)*32 + chunk*8);
            const unsigned short* P0 = (ks == 0) ? X0p : H0p;
            const unsigned short* P1 = (ks == 0) ? X1p : H1p;
            const unsigned short* P2 = (ks == 0) ? X2p : H2p;
            a0[mi] = *(const v8s*)(P0 + oa);
            a1[mi] = *(const v8s*)(P1 + oa);
            a2[mi] = *(const v8s*)(P2 + oa);
        }
        #pragma unroll
        for (int ni = 0; ni < 4; ni++) {
            size_t ob = (size_t)(wcol0 + ni*16 + l15)*KTOT + ks*32 + chunk*8;
            v8s b0 = *(const v8s*)(W0 + ob);
            v8s b1 = *(const v8s*)(W1 + ob);
            v8s b2 = *(const v8s*)(W2 + ob);
            #pragma unroll
            for (int mi = 0; mi < 4; mi++) {
                v4f c = acc[mi][ni];
                c = __builtin_amdgcn_mfma_f32_16x16x32_bf16(a0[mi], b0, c, 0, 0, 0);
                c = __builtin_amdgcn_mfma_f32_16x16x32_bf16(a0[mi], b1, c, 0, 0, 0);
                c = __builtin_amdgcn_mfma_f32_16x16x32_bf16(a1[mi], b0, c, 0, 0, 0);
                c = __builtin_amdgcn_mfma_f32_16x16x32_bf16(a0[mi], b2, c, 0, 0, 0);
                c = __builtin_amdgcn_mfma_f32_16x16x32_bf16(a1[mi], b1, c, 0, 0, 0);
                c = __builtin_amdgcn_mfma_f32_16x16x32_bf16(a2[mi], b0, c, 0, 0, 0);
                acc[mi][ni] = c;
            }
        }
    }

    // epilogue: D layout col=lane&15, row=(lane>>4)*4+r
    #pragma unroll
    for (int mi = 0; mi < 4; mi++)
        #pragma unroll
        for (int ni = 0; ni < 4; ni++) {
            int cc = wcol0 + ni*16 + l15;
            float bv = bias[cc];
            #pragma unroll
            for (int r = 0; r < 4; r++) {
                int row = row0 + mi*16 + chunk*4 + r;
                if (row >= NN) continue;
                float v = acc[mi][ni][r] + bv;
                if (EPI == 0) {
                    float s = fast_sigmoid(v);
                    if (cc < HID) {
                        p0[(size_t)row*HID + cc] = s;                      // z
                    } else {
                        int c = cc - HID;
                        float hr = p2[(size_t)row*HID + c] * s;            // hr = h*r
                        p1[(size_t)row*HID + c] = hr;
                        unsigned short u0, u1, u2; split3(hr, u0, u1, u2);
                        S0[(size_t)row*256 + c] = u0;
                        S1[(size_t)row*256 + c] = u1;
                        S2[(size_t)row*256 + c] = u2;
                    }
                } else {
                    float ht = fast_tanh(v);
                    float zz   = p0[(size_t)row*HID + cc];
                    float hold = p1[(size_t)row*HID + cc];
                    float hn = zz*hold + (1.0f - zz)*ht;                   // h update
                    p1[(size_t)row*HID + cc] = hn;
                    unsigned short u0, u1, u2; split3(hn, u0, u1, u2);
                    S0[(size_t)row*256 + cc] = u0;
                    S1[(size_t)row*256 + cc] = u1;
                    S2[(size_t)row*256 + cc] = u2;
                }
            }
        }
}

// u = h @ W_head + b_head ; 64 lanes per node (2 h-elems each), shfl reduce
__global__ void head_kernel(const float* __restrict__ h, const float* __restrict__ Whead,
                            const float* __restrict__ bhead, float* __restrict__ out) {
    int node = blockIdx.x * 4 + (threadIdx.x >> 6);
    int lane = threadIdx.x & 63;
    if (node >= NN) return;
    float h0 = h[(size_t)node*128 + lane];
    float h1 = h[(size_t)node*128 + 64 + lane];
    float p[3];
    #pragma unroll
    for (int j = 0; j < 3; j++)
        p[j] = h0 * Whead[lane*3 + j] + h1 * Whead[(64 + lane)*3 + j];
    #pragma unroll
    for (int off = 32; off > 0; off >>= 1) {
        p[0] += __shfl_down(p[0], off);
        p[1] += __shfl_down(p[1], off);
        p[2] += __shfl_down(p[2], off);
    }
    if (lane == 0) {
        out[(size_t)node*3 + 0] = p[0] + bhead[0];
        out[(size_t)node*3 + 1] = p[1] + bhead[1];
        out[(size_t)node*3 + 2] = p[2] + bhead[2];
    }
}

// ---------------- host launch ----------------

extern "C" void kernel_launch(void* const* d_in, const int* in_sizes, int n_in,
                              void* d_out, int out_size, void* d_ws, size_t ws_size,
                              hipStream_t stream) {
    const float* X_seq  = (const float*)d_in[0];   // [24,50000,11]
    const int*   eidx   = (const int*)  d_in[1];   // [2,800000]
    const float* Wx     = (const float*)d_in[2];   // [3,2,11,128]
    const float* bx     = (const float*)d_in[3];   // [3,128]
    const float* Wh     = (const float*)d_in[4];   // [3,2,128,128]
    const float* bh     = (const float*)d_in[5];   // [3,128]
    const float* Whead  = (const float*)d_in[6];   // [128,3]
    const float* bhead  = (const float*)d_in[7];   // [3]
    float* out = (float*)d_out;                    // [24,50000,3]

    const int* src = eidx;
    const int* dst = eidx + EE;

    char* base = (char*)d_ws;
    size_t off = 0;
    auto carve = [&](size_t bytes) -> void* {
        void* p = base + off;
        off += (bytes + 255) & ~(size_t)255;
        return p;
    };
    int*   deg_i   = (int*)  carve((size_t)NN * 4);
    int*   cnt     = (int*)  carve((size_t)NN * 4);
    int*   fillp   = (int*)  carve((size_t)NN * 4);
    int*   row_ptr = (int*)  carve((size_t)(NN + 1) * 4);
    float* dinv    = (float*)carve((size_t)NN * 4);
    int2*  csr     = (int2*) carve((size_t)EE * 8);
    unsigned short* WA0 = (unsigned short*)carve((size_t)256 * KTOT * 2);
    unsigned short* WA1 = (unsigned short*)carve((size_t)256 * KTOT * 2);
    unsigned short* WA2 = (unsigned short*)carve((size_t)256 * KTOT * 2);
    unsigned short* WB0 = (unsigned short*)carve((size_t)128 * KTOT * 2);
    unsigned short* WB1 = (unsigned short*)carve((size_t)128 * KTOT * 2);
    unsigned short* WB2 = (unsigned short*)carve((size_t)128 * KTOT * 2);
    float* biasA   = (float*)carve(256 * 4);
    float* biasB   = (float*)carve(128 * 4);
    float* xbuf    = (float*)carve((size_t)NN * 16 * 4);
    unsigned short* X0p = (unsigned short*)carve((size_t)NN * 32 * 2);
    unsigned short* X1p = (unsigned short*)carve((size_t)NN * 32 * 2);
    unsigned short* X2p = (unsigned short*)carve((size_t)NN * 32 * 2);
    float* hbuf    = (float*)carve((size_t)NN * 128 * 4);
    unsigned short* HA0 = (unsigned short*)carve((size_t)NN * 256 * 2);  // [h | hl] splits
    unsigned short* HA1 = (unsigned short*)carve((size_t)NN * 256 * 2);
    unsigned short* HA2 = (unsigned short*)carve((size_t)NN * 256 * 2);
    float* hrbuf   = (float*)carve((size_t)NN * 128 * 4);
    unsigned short* HB0 = (unsigned short*)carve((size_t)NN * 256 * 2);  // [hr | hrl] splits
    unsigned short* HB1 = (unsigned short*)carve((size_t)NN * 256 * 2);
    unsigned short* HB2 = (unsigned short*)carve((size_t)NN * 256 * 2);
    float* zbuf    = (float*)carve((size_t)NN * 128 * 4);
    (void)ws_size; (void)n_in; (void)in_sizes; (void)out_size;

    hipMemsetAsync(deg_i, 0, (size_t)NN * 4, stream);
    hipMemsetAsync(cnt,   0, (size_t)NN * 4, stream);
    hipMemsetAsync(fillp, 0, (size_t)NN * 4, stream);
    hipMemsetAsync(hbuf,  0, (size_t)NN * 128 * 4, stream);
    hipMemsetAsync(HA0,   0, (size_t)NN * 256 * 2, stream);   // h=0 -> zero splits at t=0
    hipMemsetAsync(HA1,   0, (size_t)NN * 256 * 2, stream);
    hipMemsetAsync(HA2,   0, (size_t)NN * 256 * 2, stream);

    count_deg_kernel<<<(EE + 255) / 256, 256, 0, stream>>>(src, dst, deg_i, cnt);
    dinv_kernel<<<(NN + 255) / 256, 256, 0, stream>>>(deg_i, dinv);
    scan_kernel<<<1, 1024, 0, stream>>>(cnt, row_ptr);
    fill_csr_kernel<<<(EE + 255) / 256, 256, 0, stream>>>(src, dst, row_ptr, fillp, dinv, csr);
    {
        int total = 256*KTOT + 128*KTOT + 256 + 128;
        pack_weights_kernel<<<(total + 255) / 256, 256, 0, stream>>>(Wx, bx, Wh, bh,
            WA0, WA1, WA2, WB0, WB1, WB2, biasA, biasB);
    }

    const int gridN256 = (NN + 255) / 256;
    const int gridM = (NN + 63) / 64;                 // 782 row-blocks; cols all in-block

    for (int t = 0; t < TT; t++) {
        if (t == 0) {
            copy_x0_kernel<<<gridN256, 256, 0, stream>>>(X_seq, xbuf, X0p, X1p, X2p);
        } else {
            const float* Xt   = X_seq + (size_t)t * NN * 11;
            const float* Xtm1 = X_seq + (size_t)(t - 1) * NN * 11;
            const float* pos  = out + (size_t)(t - 1) * NN * 3;
            const float* prevbase;
            int pstride, poff;
            if (t == 1) { prevbase = X_seq; pstride = 11; poff = 3; }
            else        { prevbase = out + (size_t)(t - 2) * NN * 3; pstride = 3; poff = 0; }
            build_x_kernel<<<gridN256, 256, 0, stream>>>(Xt, Xtm1, pos, prevbase, pstride, poff,
                                                         xbuf, X0p, X1p, X2p);
        }

        lap_small_kernel<<<(NN + 15) / 16, 256, 0, stream>>>(row_ptr, csr, xbuf, X0p, X1p, X2p);
        lap_big_kernel<<<(NN + 3) / 4, 256, 0, stream>>>(row_ptr, csr, hbuf, HA0, HA1, HA2);

        // stage A: z (cols<128) and hr (cols>=128, emits hr splits into HB*). 256 thr = 4 waves.
        gemm_mfma_kernel<256, 0><<<gridM, 256, 0, stream>>>(X0p, X1p, X2p, HA0, HA1, HA2,
                                                            WA0, WA1, WA2, biasA,
                                                            zbuf, hrbuf, hbuf, HB0, HB1, HB2);
        // lap of hr -> hrl splits into HB* cols 128-255
        lap_big_kernel<<<(NN + 3) / 4, 256, 0, stream>>>(row_ptr, csr, hrbuf, HB0, HB1, HB2);

        // stage B: h~ and h update (in place on hbuf; emits h splits into HA*). 128 thr = 2 waves.
        gemm_mfma_kernel<128, 1><<<gridM, 128, 0, stream>>>(X0p, X1p, X2p, HB0, HB1, HB2,
                                                            WB0, WB1, WB2, biasB,
                                                            zbuf, hbuf, nullptr, HA0, HA1, HA2);

        head_kernel<<<(NN + 3) / 4, 256, 0, stream>>>(hbuf, Whead, bhead, out + (size_t)t * NN * 3);
    }
}